// Round 1
// 185.268 us; speedup vs baseline: 1.0738x; 1.0738x over previous
//
#include <hip/hip_runtime.h>
#include <stdint.h>

#define EMB 1024
#define SEQL 2048
#define HEADS 16
#define HS 64

typedef __attribute__((ext_vector_type(8))) short bfx8;
typedef __attribute__((ext_vector_type(4))) float f32x4;
typedef __attribute__((ext_vector_type(4))) unsigned short us4;

__device__ __forceinline__ unsigned short f2bf(float f) {
  union { float f; unsigned u; } x; x.f = f;
  unsigned r = x.u + 0x7fffu + ((x.u >> 16) & 1u);
  return (unsigned short)(r >> 16);
}

__device__ __forceinline__ void gll16(const void* g, void* l) {
  __builtin_amdgcn_global_load_lds(
      (const __attribute__((address_space(1))) unsigned int*)g,
      (__attribute__((address_space(3))) unsigned int*)l, 16, 0, 0);
}

// ---------------- LayerNorm: x fp32 [4096][1024] -> h bf16 ----------------
__global__ __launch_bounds__(256) void ln_kernel(
    const float* __restrict__ x, const float* __restrict__ gam,
    const float* __restrict__ bet, unsigned short* __restrict__ h) {
  const int row = blockIdx.x;
  const int tid = threadIdx.x;
  const float4 v = reinterpret_cast<const float4*>(x + (size_t)row * EMB)[tid];
  float s = v.x + v.y + v.z + v.w;
  float sq = v.x * v.x + v.y * v.y + v.z * v.z + v.w * v.w;
  #pragma unroll
  for (int m = 1; m < 64; m <<= 1) {
    s += __shfl_xor(s, m, 64);
    sq += __shfl_xor(sq, m, 64);
  }
  __shared__ float red[8];
  const int lane = tid & 63, wave = tid >> 6;
  if (lane == 0) { red[wave] = s; red[wave + 4] = sq; }
  __syncthreads();
  s = red[0] + red[1] + red[2] + red[3];
  sq = red[4] + red[5] + red[6] + red[7];
  const float mu = s * (1.0f / EMB);
  const float var = sq * (1.0f / EMB) - mu * mu;
  const float rs = rsqrtf(var + 1e-5f);
  const float4 gg = reinterpret_cast<const float4*>(gam)[tid];
  const float4 bb = reinterpret_cast<const float4*>(bet)[tid];
  us4 o;
  o.x = f2bf((v.x - mu) * rs * gg.x + bb.x);
  o.y = f2bf((v.y - mu) * rs * gg.y + bb.y);
  o.z = f2bf((v.z - mu) * rs * gg.z + bb.z);
  o.w = f2bf((v.w - mu) * rs * gg.w + bb.w);
  reinterpret_cast<us4*>(h + (size_t)row * EMB)[tid] = o;
}

// ---------------- Weight fp32 -> bf16 (4 matrices packed) ----------------
__global__ __launch_bounds__(256) void cvt_kernel(
    const float* __restrict__ s0, const float* __restrict__ s1,
    const float* __restrict__ s2, const float* __restrict__ s3,
    unsigned short* __restrict__ d) {
  const int m = blockIdx.x >> 10;
  const int blk = blockIdx.x & 1023;
  const float* s = (m == 0) ? s0 : (m == 1) ? s1 : (m == 2) ? s2 : s3;
  unsigned short* dd = d + (size_t)m * EMB * EMB;
  const int idx = blk * 256 + threadIdx.x;  // float4 index
  const float4 v = reinterpret_cast<const float4*>(s)[idx];
  us4 o;
  o.x = f2bf(v.x); o.y = f2bf(v.y); o.z = f2bf(v.z); o.w = f2bf(v.w);
  reinterpret_cast<us4*>(dd)[idx] = o;
}

// ---------------- shared GEMM mainloop: C[128x128] tile, B is [N][K] -------
// LDS tiles [128][64] bf16, XOR-swizzled (byte ^= (row&7)<<4 within row).
__device__ __forceinline__ void gemm_tile(
    const unsigned short* __restrict__ Ag, const unsigned short* __restrict__ Bg,
    int m0, int n0, int K, char* lA, char* lB, f32x4 acc[4][4]) {
  const int tid = threadIdx.x;
  const int lane = tid & 63, wave = tid >> 6;
  const int g = lane >> 4, c = lane & 15;
  const int wr = wave >> 1, wc = wave & 1;

  const f32x4 zero = {0.f, 0.f, 0.f, 0.f};
  #pragma unroll
  for (int i = 0; i < 4; ++i)
    #pragma unroll
    for (int j = 0; j < 4; ++j) acc[i][j] = zero;

  const int Dbase = (wave * 4 * 64 + lane) * 16;
  for (int k0 = 0; k0 < K; k0 += 64) {
    __syncthreads();
    #pragma unroll
    for (int i = 0; i < 4; ++i) {
      const int Db = Dbase + i * 1024;      // linear byte in 16KB tile
      const int row = Db >> 7;
      const int col = ((Db & 127) ^ ((row & 7) << 4)) >> 1;  // pre-swizzled src
      gll16(Ag + (size_t)(m0 + row) * K + (k0 + col), lA + (wave * 4 + i) * 1024);
      gll16(Bg + (size_t)(n0 + row) * K + (k0 + col), lB + (wave * 4 + i) * 1024);
    }
    __syncthreads();
    #pragma unroll
    for (int kf = 0; kf < 2; ++kf) {
      bfx8 af[4], bfr[4];
      #pragma unroll
      for (int i = 0; i < 4; ++i) {
        const int ra = wr * 64 + i * 16 + c;
        af[i] = *(const bfx8*)(lA + ra * 128 + ((kf * 64 + g * 16) ^ ((ra & 7) << 4)));
        const int rb = wc * 64 + i * 16 + c;
        bfr[i] = *(const bfx8*)(lB + rb * 128 + ((kf * 64 + g * 16) ^ ((rb & 7) << 4)));
      }
      #pragma unroll
      for (int i = 0; i < 4; ++i)
        #pragma unroll
        for (int j = 0; j < 4; ++j)
          acc[i][j] = __builtin_amdgcn_mfma_f32_16x16x32_bf16(af[i], bfr[j], acc[i][j], 0, 0, 0);
    }
  }
}

// ---------------- QKV GEMM: h[4096][1024] x W{q,k,v}^T -> q,k,v bufs ------
__global__ __launch_bounds__(256, 2) void qkv_gemm(
    const unsigned short* __restrict__ h, const unsigned short* __restrict__ wbf,
    const float* __restrict__ bq, const float* __restrict__ bk,
    const float* __restrict__ bv, unsigned short* __restrict__ qb,
    unsigned short* __restrict__ kb, unsigned short* __restrict__ vtb) {
  __shared__ char lA[16384];
  __shared__ char lB[16384];
  f32x4 acc[4][4];
  const int m0 = blockIdx.x * 128;
  const int n0g = blockIdx.y * 128;
  const int mat = n0g >> 10;        // 0=q 1=k 2=v
  const int n0 = n0g & 1023;
  gemm_tile(h, wbf + (size_t)mat * EMB * EMB, m0, n0, EMB, lA, lB, acc);

  const float* bias = (mat == 0) ? bq : (mat == 1) ? bk : bv;
  const int lane = threadIdx.x & 63, wave = threadIdx.x >> 6;
  const int g = lane >> 4, c = lane & 15;
  const int wr = wave >> 1, wc = wave & 1;
  #pragma unroll
  for (int i = 0; i < 4; ++i) {
    #pragma unroll
    for (int j = 0; j < 4; ++j) {
      const int col = n0 + wc * 64 + j * 16 + c;  // 0..1023 within matrix
      const float bz = bias[col];
      const int hh = col >> 6, d = col & 63;
      #pragma unroll
      for (int r = 0; r < 4; ++r) {
        const int row = m0 + wr * 64 + i * 16 + 4 * g + r;  // 0..4095
        const int bidx = row >> 11, l = row & 2047;
        const unsigned short bv16 = f2bf(acc[i][j][r] + bz);
        if (mat < 2) {
          unsigned short* dst = (mat == 0) ? qb : kb;
          dst[(((size_t)(bidx * HEADS + hh) * SEQL + l) << 6) + d] = bv16;
        } else {
          vtb[((size_t)(bidx * HEADS + hh) * HS + d) * SEQL + l] = bv16;
        }
      }
    }
  }
}

// ---------------- Flash attention: per (qblk, b*h), 8 waves x 16 rows -----
// K/V tiles double-buffered in LDS (shared by all 8 waves = 128 q rows);
// STAGE(next) -> compute(cur) -> barrier. Softmax in log2 domain with
// defer-max rescale (THR = 8 nats); s_setprio around MFMA clusters.
__global__ __launch_bounds__(512, 4) void attn_kernel(
    const unsigned short* __restrict__ qb, const unsigned short* __restrict__ kb,
    const unsigned short* __restrict__ vtb, unsigned short* __restrict__ ob) {
  __shared__ char lK[2][8192];    // [64 keys][64 d] bf16, swizzled
  __shared__ char lV[2][8192];    // [64 d][64 keys] bf16, swizzled
  __shared__ char plds[8][2048];  // per-wave P tile [16][64] bf16, swizzled
  const int tid = threadIdx.x, lane = tid & 63, wave = tid >> 6;
  const int g = lane >> 4, c = lane & 15;
  const int qblk = blockIdx.x;  // 16
  const int bh = blockIdx.y;    // 32
  const unsigned short* qp = qb + (size_t)bh * SEQL * HS;
  const unsigned short* kp = kb + (size_t)bh * SEQL * HS;
  const unsigned short* vp = vtb + (size_t)bh * HS * SEQL;
  const int q0 = qblk * 128 + wave * 16;

  bfx8 aq[2];
  #pragma unroll
  for (int kf = 0; kf < 2; ++kf)
    aq[kf] = *(const bfx8*)(qp + (size_t)(q0 + c) * HS + kf * 32 + g * 8);

  const float SCL = 0.125f * 1.44269504089f;  // log2(e)/8 -> log2 domain
  const float THR = 11.5416f;                 // 8 nats in log2 units

  float mst[4], lst[4];
  f32x4 oacc[4];
  const f32x4 zero = {0.f, 0.f, 0.f, 0.f};
  #pragma unroll
  for (int r = 0; r < 4; ++r) { mst[r] = -INFINITY; lst[r] = 0.f; }
  #pragma unroll
  for (int nf = 0; nf < 4; ++nf) oacc[nf] = zero;
  char* pw = plds[wave];

  // staging addresses: each of 8 waves stages 1KB of each 8KB tile;
  // LDS dest linear, source column inverse-swizzled.
  const int sbase = wave * 1024;
  const int sDb = sbase + lane * 16;
  const int srow = sDb >> 7;                                 // 0..63
  const int scol = ((sDb & 127) ^ ((srow & 7) << 4)) >> 1;   // 0..63 elems
  const unsigned short* ksrc = kp + (size_t)srow * HS + scol;
  const unsigned short* vsrc = vp + (size_t)srow * SEQL + scol;

  // prologue: stage tile 0 into buffer 0
  gll16(ksrc, lK[0] + sbase);
  gll16(vsrc, lV[0] + sbase);
  __syncthreads();

  int cur = 0;
  for (int t0 = 0; t0 < SEQL; t0 += 64) {
    // issue next-tile loads (latency hides under this tile's compute)
    if (t0 + 64 < SEQL) {
      gll16(ksrc + (size_t)(t0 + 64) * HS, lK[cur ^ 1] + sbase);
      gll16(vsrc + (t0 + 64), lV[cur ^ 1] + sbase);
    }

    const char* lKc = lK[cur];
    const char* lVc = lV[cur];

    f32x4 s[4];
    #pragma unroll
    for (int nf = 0; nf < 4; ++nf) s[nf] = zero;

    __builtin_amdgcn_s_setprio(1);
    #pragma unroll
    for (int kf = 0; kf < 2; ++kf) {
      #pragma unroll
      for (int nf = 0; nf < 4; ++nf) {
        const int kr = nf * 16 + c;
        const bfx8 bk8 = *(const bfx8*)(lKc + kr * 128 + ((kf * 64 + g * 16) ^ ((kr & 7) << 4)));
        s[nf] = __builtin_amdgcn_mfma_f32_16x16x32_bf16(aq[kf], bk8, s[nf], 0, 0, 0);
      }
    }
    __builtin_amdgcn_s_setprio(0);

    // row max (log2 domain): in-lane over nf, then across the 16 c-lanes
    float mt[4];
    #pragma unroll
    for (int r = 0; r < 4; ++r) {
      const float a0 = fmaxf(fmaxf(s[0][r], s[1][r]), fmaxf(s[2][r], s[3][r]));
      mt[r] = a0 * SCL;
    }
    #pragma unroll
    for (int m = 1; m < 16; m <<= 1)
      #pragma unroll
      for (int r = 0; r < 4; ++r)
        mt[r] = fmaxf(mt[r], __shfl_xor(mt[r], m, 64));

    // defer-max: skip the O/l rescale while max growth <= 8 nats
    bool ok = true;
    #pragma unroll
    for (int r = 0; r < 4; ++r) ok = ok && (mt[r] <= mst[r] + THR);
    if (!__all(ok)) {
      #pragma unroll
      for (int r = 0; r < 4; ++r) {
        const float mn = fmaxf(mst[r], mt[r]);
        const float al = exp2f(mst[r] - mn);
        mst[r] = mn;
        lst[r] *= al;
        #pragma unroll
        for (int nf = 0; nf < 4; ++nf) oacc[nf][r] *= al;
      }
    }

    // P = exp2(s*SCL - m), write to wave-private LDS (swizzled), row sums
    float rsum[4] = {0.f, 0.f, 0.f, 0.f};
    #pragma unroll
    for (int nf = 0; nf < 4; ++nf)
      #pragma unroll
      for (int r = 0; r < 4; ++r) {
        const float p = exp2f(fmaf(s[nf][r], SCL, -mst[r]));
        rsum[r] += p;
        const int qr = 4 * g + r;
        const int off = (nf * 32 + 2 * c) ^ ((qr & 7) << 4);
        *(unsigned short*)(pw + qr * 128 + off) = f2bf(p);
      }
    #pragma unroll
    for (int m = 1; m < 16; m <<= 1)
      #pragma unroll
      for (int r = 0; r < 4; ++r)
        rsum[r] += __shfl_xor(rsum[r], m, 64);
    #pragma unroll
    for (int r = 0; r < 4; ++r) lst[r] += rsum[r];

    // PV: P from wave-private LDS, V from staged LDS tile
    __builtin_amdgcn_s_setprio(1);
    #pragma unroll
    for (int kf = 0; kf < 2; ++kf) {
      const bfx8 ap = *(const bfx8*)(pw + c * 128 + ((kf * 64 + g * 16) ^ ((c & 7) << 4)));
      #pragma unroll
      for (int nf = 0; nf < 4; ++nf) {
        const int vr = nf * 16 + c;
        const bfx8 bv8 = *(const bfx8*)(lVc + vr * 128 + ((kf * 64 + g * 16) ^ ((vr & 7) << 4)));
        oacc[nf] = __builtin_amdgcn_mfma_f32_16x16x32_bf16(ap, bv8, oacc[nf], 0, 0, 0);
      }
    }
    __builtin_amdgcn_s_setprio(0);

    __syncthreads();  // drains vmcnt: next tile staged; all waves done with cur
    cur ^= 1;
  }

  const int b = bh >> 4, hh = bh & 15;
  #pragma unroll
  for (int r = 0; r < 4; ++r) {
    const float inv = 1.f / lst[r];
    const int row = q0 + 4 * g + r;
    #pragma unroll
    for (int nf = 0; nf < 4; ++nf)
      ob[(size_t)(b * SEQL + row) * EMB + hh * 64 + nf * 16 + c] =
          f2bf(oacc[nf][r] * inv);
  }
}

// ---------------- Output GEMM: ob x Wo^T + bo -> fp32 out ----------------
__global__ __launch_bounds__(256, 2) void out_gemm(
    const unsigned short* __restrict__ ob, const unsigned short* __restrict__ wo,
    const float* __restrict__ bo, float* __restrict__ out) {
  __shared__ char lA[16384];
  __shared__ char lB[16384];
  f32x4 acc[4][4];
  const int m0 = blockIdx.x * 128;
  const int n0 = blockIdx.y * 128;
  gemm_tile(ob, wo, m0, n0, EMB, lA, lB, acc);

  const int lane = threadIdx.x & 63, wave = threadIdx.x >> 6;
  const int g = lane >> 4, c = lane & 15;
  const int wr = wave >> 1, wc = wave & 1;
  #pragma unroll
  for (int i = 0; i < 4; ++i)
    #pragma unroll
    for (int j = 0; j < 4; ++j) {
      const int col = n0 + wc * 64 + j * 16 + c;
      const float bz = bo[col];
      #pragma unroll
      for (int r = 0; r < 4; ++r) {
        const int row = m0 + wr * 64 + i * 16 + 4 * g + r;
        out[(size_t)row * EMB + col] = acc[i][j][r] + bz;
      }
    }
}

extern "C" void kernel_launch(void* const* d_in, const int* in_sizes, int n_in,
                              void* d_out, int out_size, void* d_ws, size_t ws_size,
                              hipStream_t stream) {
  const float* x   = (const float*)d_in[0];
  const float* lng = (const float*)d_in[1];
  const float* lnb = (const float*)d_in[2];
  const float* Wq  = (const float*)d_in[3];
  const float* bq  = (const float*)d_in[4];
  const float* Wk  = (const float*)d_in[5];
  const float* bk  = (const float*)d_in[6];
  const float* Wv  = (const float*)d_in[7];
  const float* bv  = (const float*)d_in[8];
  const float* Wo  = (const float*)d_in[9];
  const float* bo  = (const float*)d_in[10];

  char* ws = (char*)d_ws;
  unsigned short* h   = (unsigned short*)(ws);                  // 8 MB
  unsigned short* wbf = (unsigned short*)(ws + 8388608);        // 8 MB (q,k,v,o)
  unsigned short* qb  = (unsigned short*)(ws + 16777216);       // 8 MB [B][H][L][64]
  unsigned short* kb  = (unsigned short*)(ws + 25165824);       // 8 MB [B][H][L][64]
  unsigned short* vtb = (unsigned short*)(ws + 33554432);       // 8 MB [B][H][64][L]
  unsigned short* ob  = (unsigned short*)(ws + 41943040);       // 8 MB [B][L][1024]
  float* out = (float*)d_out;

  ln_kernel<<<dim3(4096), dim3(256), 0, stream>>>(x, lng, lnb, h);
  cvt_kernel<<<dim3(4096), dim3(256), 0, stream>>>(Wq, Wk, Wv, Wo, wbf);
  qkv_gemm<<<dim3(32, 24), dim3(256), 0, stream>>>(h, wbf, bq, bk, bv, qb, kb, vtb);
  attn_kernel<<<dim3(16, 32), dim3(512), 0, stream>>>(qb, kb, vtb, ob);
  out_gemm<<<dim3(32, 8), dim3(256), 0, stream>>>(ob, wbf + (size_t)3 * EMB * EMB, bo, out);
}

// Round 2
// 145.278 us; speedup vs baseline: 1.3694x; 1.2753x over previous
//
#include <hip/hip_runtime.h>
#include <stdint.h>

#define EMB 1024
#define SEQL 2048
#define HEADS 16
#define HS 64

typedef __attribute__((ext_vector_type(8))) short bfx8;
typedef __attribute__((ext_vector_type(4))) float f32x4;
typedef __attribute__((ext_vector_type(4))) unsigned short us4;

__device__ __forceinline__ unsigned short f2bf(float f) {
  union { float f; unsigned u; } x; x.f = f;
  unsigned r = x.u + 0x7fffu + ((x.u >> 16) & 1u);
  return (unsigned short)(r >> 16);
}

__device__ __forceinline__ unsigned cvtpk(float lo, float hi) {
  unsigned r;
  asm("v_cvt_pk_bf16_f32 %0, %1, %2" : "=v"(r) : "v"(lo), "v"(hi));
  return r;
}

__device__ __forceinline__ void gll16(const void* g, void* l) {
  __builtin_amdgcn_global_load_lds(
      (const __attribute__((address_space(1))) unsigned int*)g,
      (__attribute__((address_space(3))) unsigned int*)l, 16, 0, 0);
}

// ---------------- LayerNorm: x fp32 [4096][1024] -> h bf16 ----------------
__global__ __launch_bounds__(256) void ln_kernel(
    const float* __restrict__ x, const float* __restrict__ gam,
    const float* __restrict__ bet, unsigned short* __restrict__ h) {
  const int row = blockIdx.x;
  const int tid = threadIdx.x;
  const float4 v = reinterpret_cast<const float4*>(x + (size_t)row * EMB)[tid];
  float s = v.x + v.y + v.z + v.w;
  float sq = v.x * v.x + v.y * v.y + v.z * v.z + v.w * v.w;
  #pragma unroll
  for (int m = 1; m < 64; m <<= 1) {
    s += __shfl_xor(s, m, 64);
    sq += __shfl_xor(sq, m, 64);
  }
  __shared__ float red[8];
  const int lane = tid & 63, wave = tid >> 6;
  if (lane == 0) { red[wave] = s; red[wave + 4] = sq; }
  __syncthreads();
  s = red[0] + red[1] + red[2] + red[3];
  sq = red[4] + red[5] + red[6] + red[7];
  const float mu = s * (1.0f / EMB);
  const float var = sq * (1.0f / EMB) - mu * mu;
  const float rs = rsqrtf(var + 1e-5f);
  const float4 gg = reinterpret_cast<const float4*>(gam)[tid];
  const float4 bb = reinterpret_cast<const float4*>(bet)[tid];
  us4 o;
  o.x = f2bf((v.x - mu) * rs * gg.x + bb.x);
  o.y = f2bf((v.y - mu) * rs * gg.y + bb.y);
  o.z = f2bf((v.z - mu) * rs * gg.z + bb.z);
  o.w = f2bf((v.w - mu) * rs * gg.w + bb.w);
  reinterpret_cast<us4*>(h + (size_t)row * EMB)[tid] = o;
}

// ---------------- Weight fp32 -> bf16 (4 matrices packed) ----------------
__global__ __launch_bounds__(256) void cvt_kernel(
    const float* __restrict__ s0, const float* __restrict__ s1,
    const float* __restrict__ s2, const float* __restrict__ s3,
    unsigned short* __restrict__ d) {
  const int m = blockIdx.x >> 10;
  const int blk = blockIdx.x & 1023;
  const float* s = (m == 0) ? s0 : (m == 1) ? s1 : (m == 2) ? s2 : s3;
  unsigned short* dd = d + (size_t)m * EMB * EMB;
  const int idx = blk * 256 + threadIdx.x;  // float4 index
  const float4 v = reinterpret_cast<const float4*>(s)[idx];
  us4 o;
  o.x = f2bf(v.x); o.y = f2bf(v.y); o.z = f2bf(v.z); o.w = f2bf(v.w);
  reinterpret_cast<us4*>(dd)[idx] = o;
}

// ---------------- shared GEMM mainloop: C[128x128] tile, B is [N][K] -------
// LDS tiles [128][64] bf16, XOR-swizzled (byte ^= (row&7)<<4 within row).
__device__ __forceinline__ void gemm_tile(
    const unsigned short* __restrict__ Ag, const unsigned short* __restrict__ Bg,
    int m0, int n0, int K, char* lA, char* lB, f32x4 acc[4][4]) {
  const int tid = threadIdx.x;
  const int lane = tid & 63, wave = tid >> 6;
  const int g = lane >> 4, c = lane & 15;
  const int wr = wave >> 1, wc = wave & 1;

  const f32x4 zero = {0.f, 0.f, 0.f, 0.f};
  #pragma unroll
  for (int i = 0; i < 4; ++i)
    #pragma unroll
    for (int j = 0; j < 4; ++j) acc[i][j] = zero;

  const int Dbase = (wave * 4 * 64 + lane) * 16;
  for (int k0 = 0; k0 < K; k0 += 64) {
    __syncthreads();
    #pragma unroll
    for (int i = 0; i < 4; ++i) {
      const int Db = Dbase + i * 1024;      // linear byte in 16KB tile
      const int row = Db >> 7;
      const int col = ((Db & 127) ^ ((row & 7) << 4)) >> 1;  // pre-swizzled src
      gll16(Ag + (size_t)(m0 + row) * K + (k0 + col), lA + (wave * 4 + i) * 1024);
      gll16(Bg + (size_t)(n0 + row) * K + (k0 + col), lB + (wave * 4 + i) * 1024);
    }
    __syncthreads();
    #pragma unroll
    for (int kf = 0; kf < 2; ++kf) {
      bfx8 af[4], bfr[4];
      #pragma unroll
      for (int i = 0; i < 4; ++i) {
        const int ra = wr * 64 + i * 16 + c;
        af[i] = *(const bfx8*)(lA + ra * 128 + ((kf * 64 + g * 16) ^ ((ra & 7) << 4)));
        const int rb = wc * 64 + i * 16 + c;
        bfr[i] = *(const bfx8*)(lB + rb * 128 + ((kf * 64 + g * 16) ^ ((rb & 7) << 4)));
      }
      #pragma unroll
      for (int i = 0; i < 4; ++i)
        #pragma unroll
        for (int j = 0; j < 4; ++j)
          acc[i][j] = __builtin_amdgcn_mfma_f32_16x16x32_bf16(af[i], bfr[j], acc[i][j], 0, 0, 0);
    }
  }
}

// ---------------- QKV GEMM: h[4096][1024] x W{q,k,v}^T -> q,k,v bufs ------
__global__ __launch_bounds__(256, 2) void qkv_gemm(
    const unsigned short* __restrict__ h, const unsigned short* __restrict__ wbf,
    const float* __restrict__ bq, const float* __restrict__ bk,
    const float* __restrict__ bv, unsigned short* __restrict__ qb,
    unsigned short* __restrict__ kb, unsigned short* __restrict__ vtb) {
  __shared__ char lA[16384];
  __shared__ char lB[16384];
  f32x4 acc[4][4];
  const int m0 = blockIdx.x * 128;
  const int n0g = blockIdx.y * 128;
  const int mat = n0g >> 10;        // 0=q 1=k 2=v
  const int n0 = n0g & 1023;
  gemm_tile(h, wbf + (size_t)mat * EMB * EMB, m0, n0, EMB, lA, lB, acc);

  const float* bias = (mat == 0) ? bq : (mat == 1) ? bk : bv;
  const int lane = threadIdx.x & 63, wave = threadIdx.x >> 6;
  const int g = lane >> 4, c = lane & 15;
  const int wr = wave >> 1, wc = wave & 1;
  #pragma unroll
  for (int i = 0; i < 4; ++i) {
    #pragma unroll
    for (int j = 0; j < 4; ++j) {
      const int col = n0 + wc * 64 + j * 16 + c;  // 0..1023 within matrix
      const float bz = bias[col];
      const int hh = col >> 6, d = col & 63;
      #pragma unroll
      for (int r = 0; r < 4; ++r) {
        const int row = m0 + wr * 64 + i * 16 + 4 * g + r;  // 0..4095
        const int bidx = row >> 11, l = row & 2047;
        const unsigned short bv16 = f2bf(acc[i][j][r] + bz);
        if (mat < 2) {
          unsigned short* dst = (mat == 0) ? qb : kb;
          dst[(((size_t)(bidx * HEADS + hh) * SEQL + l) << 6) + d] = bv16;
        } else {
          vtb[((size_t)(bidx * HEADS + hh) * HS + d) * SEQL + l] = bv16;
        }
      }
    }
  }
}

// ---------------- Flash attention: per (qblk, b*h), 8 waves x 16 rows -----
// Swapped QK^T (S^T layout: q = lane&15, k = 16nf+4g+r) -> per-lane scalar
// running max, no per-tile cross-lane reduction on the fast path.
// Row-sum via ones-MFMA on the P fragments (shared with PV). P stored packed
// via v_cvt_pk_bf16_f32 + ds_write_b64. K/V double-buffered in LDS.
__global__ __launch_bounds__(512, 4) void attn_kernel(
    const unsigned short* __restrict__ qb, const unsigned short* __restrict__ kb,
    const unsigned short* __restrict__ vtb, unsigned short* __restrict__ ob) {
  __shared__ char lK[2][8192];    // [64 keys][64 d] bf16, swizzled
  __shared__ char lV[2][8192];    // [64 d][64 keys] bf16, swizzled
  __shared__ char plds[8][2048];  // per-wave P tile [16 q][64 k] bf16, swizzled
  const int tid = threadIdx.x, lane = tid & 63, wave = tid >> 6;
  const int g = lane >> 4, c = lane & 15;
  const int qblk = blockIdx.x;  // 16
  const int bh = blockIdx.y;    // 32
  const unsigned short* qp = qb + (size_t)bh * SEQL * HS;
  const unsigned short* kp = kb + (size_t)bh * SEQL * HS;
  const unsigned short* vp = vtb + (size_t)bh * HS * SEQL;
  const int q0 = qblk * 128 + wave * 16;

  bfx8 aq[2];
  #pragma unroll
  for (int kf = 0; kf < 2; ++kf)
    aq[kf] = *(const bfx8*)(qp + (size_t)(q0 + c) * HS + kf * 32 + g * 8);

  const float SCL = 0.125f * 1.44269504089f;  // log2(e)/8 -> log2 domain
  const float THR = 11.5416f;                 // 8 nats in log2 units
  const bfx8 vone = {0x3F80, 0x3F80, 0x3F80, 0x3F80, 0x3F80, 0x3F80, 0x3F80, 0x3F80};

  float mst = -INFINITY;   // running max for q-row = c (per-lane scalar)
  f32x4 lacc;              // row-sum accumulator (q = 4g+r), via ones-MFMA
  f32x4 oacc[4];
  const f32x4 zero = {0.f, 0.f, 0.f, 0.f};
  lacc = zero;
  #pragma unroll
  for (int nf = 0; nf < 4; ++nf) oacc[nf] = zero;
  char* pw = plds[wave];
  const int psw = (c & 7) << 4;          // P swizzle for this lane's q-row
  char* pwr = pw + c * 128;              // write/read row base (q = c)

  // staging addresses: each of 8 waves stages 1KB of each 8KB tile;
  // LDS dest linear, source column inverse-swizzled.
  const int sbase = wave * 1024;
  const int sDb = sbase + lane * 16;
  const int srow = sDb >> 7;                                 // 0..63
  const int scol = ((sDb & 127) ^ ((srow & 7) << 4)) >> 1;   // 0..63 elems
  const unsigned short* ksrc = kp + (size_t)srow * HS + scol;
  const unsigned short* vsrc = vp + (size_t)srow * SEQL + scol;

  // prologue: stage tile 0 into buffer 0
  gll16(ksrc, lK[0] + sbase);
  gll16(vsrc, lV[0] + sbase);
  __syncthreads();

  int cur = 0;
  for (int t0 = 0; t0 < SEQL; t0 += 64) {
    // issue next-tile loads (latency hides under this tile's compute)
    if (t0 + 64 < SEQL) {
      gll16(ksrc + (size_t)(t0 + 64) * HS, lK[cur ^ 1] + sbase);
      gll16(vsrc + (t0 + 64), lV[cur ^ 1] + sbase);
    }

    const char* lKc = lK[cur];
    const char* lVc = lV[cur];

    f32x4 s[4];
    #pragma unroll
    for (int nf = 0; nf < 4; ++nf) s[nf] = zero;

    // QK^T swapped: D = K_tile . Q^T = S^T ; row(4g+r)=k-local, col(c)=q-row
    __builtin_amdgcn_s_setprio(1);
    #pragma unroll
    for (int kf = 0; kf < 2; ++kf) {
      #pragma unroll
      for (int nf = 0; nf < 4; ++nf) {
        const int kr = nf * 16 + c;
        const bfx8 bk8 = *(const bfx8*)(lKc + kr * 128 + ((kf * 64 + g * 16) ^ ((kr & 7) << 4)));
        s[nf] = __builtin_amdgcn_mfma_f32_16x16x32_bf16(bk8, aq[kf], s[nf], 0, 0, 0);
      }
    }
    __builtin_amdgcn_s_setprio(0);

    // e = s*SCL - mst (mst is this lane's q-row running max, log2 domain)
    float e[4][4];
    float em[4];
    #pragma unroll
    for (int nf = 0; nf < 4; ++nf) {
      #pragma unroll
      for (int r = 0; r < 4; ++r) e[nf][r] = fmaf(s[nf][r], SCL, -mst);
      em[nf] = fmaxf(fmaxf(e[nf][0], e[nf][1]), fmaxf(e[nf][2], e[nf][3]));
    }
    const float emax = fmaxf(fmaxf(em[0], em[1]), fmaxf(em[2], em[3]));

    if (__any(emax > THR)) {
      // slow path (~once per wave): true row max, rescale accumulators
      float mt = -INFINITY;
      #pragma unroll
      for (int nf = 0; nf < 4; ++nf)
        #pragma unroll
        for (int r = 0; r < 4; ++r) mt = fmaxf(mt, s[nf][r]);
      mt *= SCL;
      mt = fmaxf(mt, __shfl_xor(mt, 16, 64));
      mt = fmaxf(mt, __shfl_xor(mt, 32, 64));
      const float mn = fmaxf(mst, mt);
      const float al = exp2f(mst - mn);  // 0 on first tile
      mst = mn;
      float alq[4];
      #pragma unroll
      for (int r = 0; r < 4; ++r) alq[r] = __shfl(al, 4 * g + r, 64);
      #pragma unroll
      for (int r = 0; r < 4; ++r) {
        lacc[r] *= alq[r];
        #pragma unroll
        for (int nf = 0; nf < 4; ++nf) oacc[nf][r] *= alq[r];
      }
      #pragma unroll
      for (int nf = 0; nf < 4; ++nf)
        #pragma unroll
        for (int r = 0; r < 4; ++r) e[nf][r] = fmaf(s[nf][r], SCL, -mst);
    }

    // P = exp2(e) -> packed bf16 pairs -> wave-private LDS (b64 writes)
    #pragma unroll
    for (int nf = 0; nf < 4; ++nf) {
      uint2 w;
      w.x = cvtpk(exp2f(e[nf][0]), exp2f(e[nf][1]));
      w.y = cvtpk(exp2f(e[nf][2]), exp2f(e[nf][3]));
      *reinterpret_cast<uint2*>(pwr + ((32 * nf + 8 * g) ^ psw)) = w;
    }

    // PV + row-sum: A = P fragment (q=c rows), B = V tile / ones
    __builtin_amdgcn_s_setprio(1);
    #pragma unroll
    for (int kf = 0; kf < 2; ++kf) {
      const bfx8 ap = *(const bfx8*)(pwr + ((kf * 64 + g * 16) ^ psw));
      lacc = __builtin_amdgcn_mfma_f32_16x16x32_bf16(ap, vone, lacc, 0, 0, 0);
      #pragma unroll
      for (int nf = 0; nf < 4; ++nf) {
        const int vr = nf * 16 + c;
        const bfx8 bv8 = *(const bfx8*)(lVc + vr * 128 + ((kf * 64 + g * 16) ^ ((vr & 7) << 4)));
        oacc[nf] = __builtin_amdgcn_mfma_f32_16x16x32_bf16(ap, bv8, oacc[nf], 0, 0, 0);
      }
    }
    __builtin_amdgcn_s_setprio(0);

    __syncthreads();  // drains vmcnt: next tile staged; all waves done with cur
    cur ^= 1;
  }

  const int b = bh >> 4, hh = bh & 15;
  #pragma unroll
  for (int r = 0; r < 4; ++r) {
    const float inv = 1.f / lacc[r];
    const int row = q0 + 4 * g + r;
    #pragma unroll
    for (int nf = 0; nf < 4; ++nf)
      ob[(size_t)(b * SEQL + row) * EMB + hh * 64 + nf * 16 + c] =
          f2bf(oacc[nf][r] * inv);
  }
}

// ---------------- Output GEMM: ob x Wo^T + bo -> fp32 out ----------------
__global__ __launch_bounds__(256, 2) void out_gemm(
    const unsigned short* __restrict__ ob, const unsigned short* __restrict__ wo,
    const float* __restrict__ bo, float* __restrict__ out) {
  __shared__ char lA[16384];
  __shared__ char lB[16384];
  f32x4 acc[4][4];
  const int m0 = blockIdx.x * 128;
  const int n0 = blockIdx.y * 128;
  gemm_tile(ob, wo, m0, n0, EMB, lA, lB, acc);

  const int lane = threadIdx.x & 63, wave = threadIdx.x >> 6;
  const int g = lane >> 4, c = lane & 15;
  const int wr = wave >> 1, wc = wave & 1;
  #pragma unroll
  for (int i = 0; i < 4; ++i)
    #pragma unroll
    for (int j = 0; j < 4; ++j) {
      const int col = n0 + wc * 64 + j * 16 + c;
      const float bz = bo[col];
      #pragma unroll
      for (int r = 0; r < 4; ++r) {
        const int row = m0 + wr * 64 + i * 16 + 4 * g + r;
        out[(size_t)row * EMB + col] = acc[i][j][r] + bz;
      }
    }
}

extern "C" void kernel_launch(void* const* d_in, const int* in_sizes, int n_in,
                              void* d_out, int out_size, void* d_ws, size_t ws_size,
                              hipStream_t stream) {
  const float* x   = (const float*)d_in[0];
  const float* lng = (const float*)d_in[1];
  const float* lnb = (const float*)d_in[2];
  const float* Wq  = (const float*)d_in[3];
  const float* bq  = (const float*)d_in[4];
  const float* Wk  = (const float*)d_in[5];
  const float* bk  = (const float*)d_in[6];
  const float* Wv  = (const float*)d_in[7];
  const float* bv  = (const float*)d_in[8];
  const float* Wo  = (const float*)d_in[9];
  const float* bo  = (const float*)d_in[10];

  char* ws = (char*)d_ws;
  unsigned short* h   = (unsigned short*)(ws);                  // 8 MB
  unsigned short* wbf = (unsigned short*)(ws + 8388608);        // 8 MB (q,k,v,o)
  unsigned short* qb  = (unsigned short*)(ws + 16777216);       // 8 MB [B][H][L][64]
  unsigned short* kb  = (unsigned short*)(ws + 25165824);       // 8 MB [B][H][L][64]
  unsigned short* vtb = (unsigned short*)(ws + 33554432);       // 8 MB [B][H][64][L]
  unsigned short* ob  = (unsigned short*)(ws + 41943040);       // 8 MB [B][L][1024]
  float* out = (float*)d_out;

  ln_kernel<<<dim3(4096), dim3(256), 0, stream>>>(x, lng, lnb, h);
  cvt_kernel<<<dim3(4096), dim3(256), 0, stream>>>(Wq, Wk, Wv, Wo, wbf);
  qkv_gemm<<<dim3(32, 24), dim3(256), 0, stream>>>(h, wbf, bq, bk, bv, qb, kb, vtb);
  attn_kernel<<<dim3(16, 32), dim3(512), 0, stream>>>(qb, kb, vtb, ob);
  out_gemm<<<dim3(32, 8), dim3(256), 0, stream>>>(ob, wbf + (size_t)3 * EMB * EMB, bo, out);
}